// Round 1
// baseline (539.163 us; speedup 1.0000x reference)
//
#include <hip/hip_runtime.h>
#include <cstdint>
#include <cstddef>

#define NHEADS 4
#define OUT_C 32
#define HC 128          // NHEADS*OUT_C
#define IN_CH 128
#define NEG_SLOPE 0.2f

static inline size_t align256(size_t v) { return (v + 255) & ~(size_t)255; }

__device__ __forceinline__ float lrelu(float v) { return v > 0.f ? v : NEG_SLOPE * v; }

__device__ __forceinline__ float wred_max(float v) {
    v = fmaxf(v, __shfl_xor(v, 1));
    v = fmaxf(v, __shfl_xor(v, 2));
    v = fmaxf(v, __shfl_xor(v, 4));
    v = fmaxf(v, __shfl_xor(v, 8));
    v = fmaxf(v, __shfl_xor(v, 16));
    v = fmaxf(v, __shfl_xor(v, 32));
    return v;
}
__device__ __forceinline__ float wred_sum(float v) {
    v += __shfl_xor(v, 1);
    v += __shfl_xor(v, 2);
    v += __shfl_xor(v, 4);
    v += __shfl_xor(v, 8);
    v += __shfl_xor(v, 16);
    v += __shfl_xor(v, 32);
    return v;
}

// ---------------------------------------------------------------------------
// Detect whether edge_index is int64 (odd 4B words all zero for values<2^31)
// or int32. Writes flag=1 for int64, 0 for int32.
__global__ void detect_dtype(const int* __restrict__ ei, int* __restrict__ flag) {
    __shared__ int red[256];
    int t = threadIdx.x;
    int acc = 0;
    for (int i = t; i < 1024; i += 256) acc |= ei[2 * i + 1];
    red[t] = acc;
    __syncthreads();
    for (int s = 128; s > 0; s >>= 1) {
        if (t < s) red[t] |= red[t + s];
        __syncthreads();
    }
    if (t == 0) *flag = (red[0] == 0) ? 1 : 0;
}

// ---------------------------------------------------------------------------
// W [128 out][128 in] -> wt [k][o] transposed copy (tiny)
__global__ void wtrans(const float* __restrict__ W, float* __restrict__ wt) {
    int idx = blockIdx.x * 256 + threadIdx.x;
    if (idx < 128 * 128) {
        int k = idx >> 7, o = idx & 127;
        wt[idx] = W[o * 128 + k];
    }
}

// ---------------------------------------------------------------------------
// h[n][128] = x[n][128] @ W^T   (fp32 VALU GEMM, 64 rows/block)
__global__ __launch_bounds__(256) void gemm_h(const float* __restrict__ x,
                                              const float* __restrict__ wtg,
                                              float* __restrict__ h, int n) {
    __shared__ float xs[64][132];   // +4 pad: kills bank conflicts on row reads
    __shared__ float wt[32][132];
    int tid = threadIdx.x;
    int rowbase = blockIdx.x << 6;
    const float4* x4 = (const float4*)x;
#pragma unroll
    for (int i = 0; i < 8; ++i) {
        int f4 = (i << 8) + tid;          // 0..2047
        int r = f4 >> 5, cc = (f4 & 31) << 2;
        int row = rowbase + r;
        if (row >= n) row = n - 1;        // clamp; stores guarded below
        float4 v = x4[((size_t)row << 5) + (cc >> 2)];
        *(float4*)&xs[r][cc] = v;
    }
    int rg = tid >> 4, cg = tid & 15;     // 16 row-groups x 16 col-groups
    float acc[4][8];
#pragma unroll
    for (int a = 0; a < 4; ++a)
#pragma unroll
        for (int b = 0; b < 8; ++b) acc[a][b] = 0.f;

    for (int kc = 0; kc < 128; kc += 32) {
        __syncthreads();
        const float4* wg4 = (const float4*)(wtg + (size_t)kc * 128);
#pragma unroll
        for (int i = 0; i < 4; ++i) {
            int f4 = (i << 8) + tid;      // 0..1023
            int kk = f4 >> 5, oo = (f4 & 31) << 2;
            *(float4*)&wt[kk][oo] = wg4[f4];
        }
        __syncthreads();
#pragma unroll
        for (int k = 0; k < 32; k += 4) {
            float xk[4][4];
#pragma unroll
            for (int rr = 0; rr < 4; ++rr) {
                float4 t = *(const float4*)&xs[(rg << 2) + rr][kc + k];
                xk[rr][0] = t.x; xk[rr][1] = t.y; xk[rr][2] = t.z; xk[rr][3] = t.w;
            }
#pragma unroll
            for (int kk = 0; kk < 4; ++kk) {
                float4 wa = *(const float4*)&wt[k + kk][cg << 3];
                float4 wb = *(const float4*)&wt[k + kk][(cg << 3) + 4];
                float wv[8] = {wa.x, wa.y, wa.z, wa.w, wb.x, wb.y, wb.z, wb.w};
#pragma unroll
                for (int rr = 0; rr < 4; ++rr)
#pragma unroll
                    for (int jj = 0; jj < 8; ++jj)
                        acc[rr][jj] = fmaf(xk[rr][kk], wv[jj], acc[rr][jj]);
            }
        }
    }
#pragma unroll
    for (int rr = 0; rr < 4; ++rr) {
        int row = rowbase + (rg << 2) + rr;
        if (row < n) {
            float4 o1 = {acc[rr][0], acc[rr][1], acc[rr][2], acc[rr][3]};
            float4 o2 = {acc[rr][4], acc[rr][5], acc[rr][6], acc[rr][7]};
            float4* hp = (float4*)(h + ((size_t)row << 7) + (cg << 3));
            hp[0] = o1;
            hp[1] = o2;
        }
    }
}

// ---------------------------------------------------------------------------
// a_src[n][h] = <h[n][h*32:+32], att_src[h]>, same for dst
__global__ void att_logits(const float* __restrict__ h, const float* __restrict__ att_src,
                           const float* __restrict__ att_dst, float* __restrict__ a_src,
                           float* __restrict__ a_dst, int n) {
    int idx = blockIdx.x * 256 + threadIdx.x;
    if (idx >= n * NHEADS) return;
    int hd = idx & 3;
    const float4* hp = (const float4*)(h + ((size_t)(idx >> 2) << 7) + (hd << 5));
    const float4* av4 = (const float4*)(att_src + (hd << 5));
    const float4* bv4 = (const float4*)(att_dst + (hd << 5));
    float ss = 0.f, dd = 0.f;
#pragma unroll
    for (int j = 0; j < 8; ++j) {
        float4 hv = hp[j];
        float4 av = av4[j];
        float4 bv = bv4[j];
        ss += hv.x * av.x + hv.y * av.y + hv.z * av.z + hv.w * av.w;
        dd += hv.x * bv.x + hv.y * bv.y + hv.z * bv.z + hv.w * bv.w;
    }
    a_src[idx] = ss;
    a_dst[idx] = dd;
}

// ---------------------------------------------------------------------------
// histogram of dst (edges only; self-loops added as +1 in scan)
__global__ void hist(const int* __restrict__ ei, const int* __restrict__ flag,
                     int* __restrict__ deg, int E) {
    int i = blockIdx.x * 256 + threadIdx.x;
    if (i >= E) return;
    int f64 = *flag;
    int d = f64 ? ei[2 * ((size_t)E + i)] : ei[(size_t)E + i];
    atomicAdd(&deg[d], 1);
}

// chunked exclusive scan, chunk=2048 (256 thr x 8)
__global__ void scan1(const int* __restrict__ deg, int* __restrict__ off,
                      int* __restrict__ tot, int n) {
    __shared__ int ts[256];
    int t = threadIdx.x;
    int i0 = (blockIdx.x << 11) + (t << 3);
    int pref[8];
    int sum = 0;
#pragma unroll
    for (int j = 0; j < 8; ++j) {
        int i = i0 + j;
        int v = (i < n) ? (deg[i] + 1) : 0;  // +1 = self loop
        pref[j] = sum;
        sum += v;
    }
    ts[t] = sum;
    __syncthreads();
    int run = sum;
    for (int d = 1; d < 256; d <<= 1) {
        int o = (t >= d) ? ts[t - d] : 0;
        __syncthreads();
        run += o;
        ts[t] = run;
        __syncthreads();
    }
    int excl = run - sum;
#pragma unroll
    for (int j = 0; j < 8; ++j) {
        int i = i0 + j;
        if (i < n) off[i] = excl + pref[j];
    }
    if (t == 255) tot[blockIdx.x] = run;
}

__global__ void scan2(const int* __restrict__ tot, int* __restrict__ cbase, int nc) {
    int lane = threadIdx.x;  // 64 threads, 1 wave
    int carry = 0;
    for (int b = 0; b < nc; b += 64) {
        int i = b + lane;
        int v = (i < nc) ? tot[i] : 0;
        int orig = v;
        for (int d = 1; d < 64; d <<= 1) {
            int u = __shfl_up(v, d);
            if (lane >= d) v += u;
        }
        if (i < nc) cbase[i] = carry + v - orig;
        carry += __shfl(v, 63);
    }
}

__global__ void finalize(int* __restrict__ off, const int* __restrict__ cbase, int n, int E) {
    int i = blockIdx.x * 256 + threadIdx.x;
    if (i < n) off[i] += cbase[i >> 11];
    else if (i == n) off[n] = E + n;
}

__global__ void scatter(const int* __restrict__ ei, const int* __restrict__ flag,
                        const int* __restrict__ off, int* __restrict__ cursor,
                        int* __restrict__ sorted, int E, int n) {
    int i = blockIdx.x * 256 + threadIdx.x;
    if (i >= E + n) return;
    int f64 = *flag;
    int s, d;
    if (i < E) {
        if (f64) { s = ei[2 * (size_t)i]; d = ei[2 * ((size_t)E + i)]; }
        else     { s = ei[i];             d = ei[(size_t)E + i]; }
    } else {
        s = d = i - E;  // self loop
    }
    int pos = off[d] + atomicAdd(&cursor[d], 1);
    sorted[pos] = s;
}

// ---------------------------------------------------------------------------
// One wave per destination node: segment softmax + weighted aggregation.
__global__ __launch_bounds__(256) void aggregate(const float* __restrict__ h,
                                                 const float* __restrict__ a_src,
                                                 const float* __restrict__ a_dst,
                                                 const int* __restrict__ off,
                                                 const int* __restrict__ sorted,
                                                 const float* __restrict__ bias,
                                                 float* __restrict__ agg, int n) {
    const float NEG_BIG = -1e30f;
    int lane = threadIdx.x & 63;
    int wid = blockIdx.x * (blockDim.x >> 6) + (threadIdx.x >> 6);
    int nw = gridDim.x * (blockDim.x >> 6);
    bool lo = lane < 32;
    float b0 = bias[lane], b1 = bias[lane + 64];
    const float4* as4 = (const float4*)a_src;
    const float4* ad4 = (const float4*)a_dst;

    for (int node = wid; node < n; node += nw) {
        int start = off[node], end = off[node + 1];
        int deg = end - start;          // >= 1 (self loop)
        float4 ad = ad4[node];
        float acc0 = 0.f, acc1 = 0.f;
        float i0, i1, i2, i3;

        if (deg <= 64) {
            bool v = lane < deg;
            int s = v ? sorted[start + lane] : 0;
            float4 as = v ? as4[s] : make_float4(0.f, 0.f, 0.f, 0.f);
            float e0 = v ? lrelu(as.x + ad.x) : NEG_BIG;
            float e1 = v ? lrelu(as.y + ad.y) : NEG_BIG;
            float e2 = v ? lrelu(as.z + ad.z) : NEG_BIG;
            float e3 = v ? lrelu(as.w + ad.w) : NEG_BIG;
            float m0 = wred_max(e0), m1 = wred_max(e1);
            float m2 = wred_max(e2), m3 = wred_max(e3);
            float p0 = v ? __expf(e0 - m0) : 0.f;
            float p1 = v ? __expf(e1 - m1) : 0.f;
            float p2 = v ? __expf(e2 - m2) : 0.f;
            float p3 = v ? __expf(e3 - m3) : 0.f;
            float s0 = wred_sum(p0), s1 = wred_sum(p1);
            float s2 = wred_sum(p2), s3 = wred_sum(p3);
            i0 = 1.f / s0; i1 = 1.f / s1; i2 = 1.f / s2; i3 = 1.f / s3;
            for (int j = 0; j < deg; ++j) {
                int sj = __shfl(s, j);
                float q0 = __shfl(p0, j), q1 = __shfl(p1, j);
                float q2 = __shfl(p2, j), q3 = __shfl(p3, j);
                float pa = lo ? q0 : q1, pb = lo ? q2 : q3;
                const float* hp = h + ((size_t)sj << 7);
                acc0 = fmaf(pa, hp[lane], acc0);
                acc1 = fmaf(pb, hp[lane + 64], acc1);
            }
        } else {
            // general chunked path (rare: max degree ~45 for this graph)
            float m0 = NEG_BIG, m1 = NEG_BIG, m2 = NEG_BIG, m3 = NEG_BIG;
            for (int bb = 0; bb < deg; bb += 64) {
                int i = bb + lane;
                bool v = i < deg;
                int s = v ? sorted[start + i] : 0;
                float4 as = v ? as4[s] : make_float4(0.f, 0.f, 0.f, 0.f);
                if (v) {
                    m0 = fmaxf(m0, lrelu(as.x + ad.x));
                    m1 = fmaxf(m1, lrelu(as.y + ad.y));
                    m2 = fmaxf(m2, lrelu(as.z + ad.z));
                    m3 = fmaxf(m3, lrelu(as.w + ad.w));
                }
            }
            m0 = wred_max(m0); m1 = wred_max(m1); m2 = wred_max(m2); m3 = wred_max(m3);
            float s0 = 0.f, s1 = 0.f, s2 = 0.f, s3 = 0.f;
            for (int bb = 0; bb < deg; bb += 64) {
                int i = bb + lane;
                bool v = i < deg;
                int s = v ? sorted[start + i] : 0;
                float4 as = v ? as4[s] : make_float4(0.f, 0.f, 0.f, 0.f);
                if (v) {
                    s0 += __expf(lrelu(as.x + ad.x) - m0);
                    s1 += __expf(lrelu(as.y + ad.y) - m1);
                    s2 += __expf(lrelu(as.z + ad.z) - m2);
                    s3 += __expf(lrelu(as.w + ad.w) - m3);
                }
            }
            s0 = wred_sum(s0); s1 = wred_sum(s1); s2 = wred_sum(s2); s3 = wred_sum(s3);
            i0 = 1.f / s0; i1 = 1.f / s1; i2 = 1.f / s2; i3 = 1.f / s3;
            for (int bb = 0; bb < deg; bb += 64) {
                int i = bb + lane;
                bool v = i < deg;
                int s = v ? sorted[start + i] : 0;
                float4 as = v ? as4[s] : make_float4(0.f, 0.f, 0.f, 0.f);
                float p0 = v ? __expf(lrelu(as.x + ad.x) - m0) : 0.f;
                float p1 = v ? __expf(lrelu(as.y + ad.y) - m1) : 0.f;
                float p2 = v ? __expf(lrelu(as.z + ad.z) - m2) : 0.f;
                float p3 = v ? __expf(lrelu(as.w + ad.w) - m3) : 0.f;
                int cl = deg - bb;
                if (cl > 64) cl = 64;
                for (int j = 0; j < cl; ++j) {
                    int sj = __shfl(s, j);
                    float q0 = __shfl(p0, j), q1 = __shfl(p1, j);
                    float q2 = __shfl(p2, j), q3 = __shfl(p3, j);
                    float pa = lo ? q0 : q1, pb = lo ? q2 : q3;
                    const float* hp = h + ((size_t)sj << 7);
                    acc0 = fmaf(pa, hp[lane], acc0);
                    acc1 = fmaf(pb, hp[lane + 64], acc1);
                }
            }
        }
        float ia = lo ? i0 : i1, ib = lo ? i2 : i3;
        size_t ob = (size_t)node << 7;
        agg[ob + lane] = acc0 * ia + b0;
        agg[ob + 64 + lane] = acc1 * ib + b1;
    }
}

// ---------------------------------------------------------------------------
// out[n][32] = elu(agg[n][128] @ W_lin^T + b_lin)
__global__ __launch_bounds__(256) void proj(const float* __restrict__ agg,
                                            const float* __restrict__ W_lin,
                                            const float* __restrict__ b_lin,
                                            float* __restrict__ out, int n) {
    __shared__ float xs[64][132];
    __shared__ float wt[128][36];   // wt[k][o]
    int tid = threadIdx.x;
    const float4* w4 = (const float4*)W_lin;
#pragma unroll
    for (int i = 0; i < 4; ++i) {
        int f4 = (i << 8) + tid;          // 0..1023
        int o = f4 >> 5, kk = (f4 & 31) << 2;
        float4 w = w4[f4];
        wt[kk][o] = w.x;
        wt[kk + 1][o] = w.y;
        wt[kk + 2][o] = w.z;
        wt[kk + 3][o] = w.w;
    }
    int rowbase = blockIdx.x << 6;
    const float4* a4 = (const float4*)agg;
#pragma unroll
    for (int i = 0; i < 8; ++i) {
        int f4 = (i << 8) + tid;          // 0..2047
        int r = f4 >> 5, cc = (f4 & 31) << 2;
        int row = rowbase + r;
        if (row >= n) row = n - 1;
        *(float4*)&xs[r][cc] = a4[((size_t)row << 5) + (cc >> 2)];
    }
    __syncthreads();
    int r = tid >> 2, cg = tid & 3, c0 = cg << 3;
    float acc[8];
#pragma unroll
    for (int j = 0; j < 8; ++j) acc[j] = 0.f;
    for (int k = 0; k < 128; k += 4) {
        float4 xv = *(const float4*)&xs[r][k];
        float xk[4] = {xv.x, xv.y, xv.z, xv.w};
#pragma unroll
        for (int kk = 0; kk < 4; ++kk) {
            float4 wa = *(const float4*)&wt[k + kk][c0];
            float4 wb = *(const float4*)&wt[k + kk][c0 + 4];
            acc[0] = fmaf(xk[kk], wa.x, acc[0]);
            acc[1] = fmaf(xk[kk], wa.y, acc[1]);
            acc[2] = fmaf(xk[kk], wa.z, acc[2]);
            acc[3] = fmaf(xk[kk], wa.w, acc[3]);
            acc[4] = fmaf(xk[kk], wb.x, acc[4]);
            acc[5] = fmaf(xk[kk], wb.y, acc[5]);
            acc[6] = fmaf(xk[kk], wb.z, acc[6]);
            acc[7] = fmaf(xk[kk], wb.w, acc[7]);
        }
    }
    int row = rowbase + r;
    if (row < n) {
        float res[8];
#pragma unroll
        for (int j = 0; j < 8; ++j) {
            float v = acc[j] + b_lin[c0 + j];
            res[j] = v > 0.f ? v : (__expf(v) - 1.f);
        }
        float4* op = (float4*)(out + (size_t)row * 32 + c0);
        op[0] = make_float4(res[0], res[1], res[2], res[3]);
        op[1] = make_float4(res[4], res[5], res[6], res[7]);
    }
}

// ---------------------------------------------------------------------------
extern "C" void kernel_launch(void* const* d_in, const int* in_sizes, int n_in,
                              void* d_out, int out_size, void* d_ws, size_t ws_size,
                              hipStream_t stream) {
    const float* x = (const float*)d_in[0];
    const int* ei = (const int*)d_in[1];
    const float* W = (const float*)d_in[2];
    const float* att_src = (const float*)d_in[3];
    const float* att_dst = (const float*)d_in[4];
    const float* bias_conv = (const float*)d_in[5];
    const float* W_lin = (const float*)d_in[6];
    const float* b_lin = (const float*)d_in[7];
    int n = in_sizes[0] / IN_CH;
    int E = in_sizes[1] / 2;

    char* ws = (char*)d_ws;
    size_t o = 0;
    auto alloc = [&](size_t bytes) { char* p = ws + o; o = align256(o + bytes); return p; };
    float* h       = (float*)alloc((size_t)n * HC * 4);
    float* agg     = (float*)alloc((size_t)n * HC * 4);
    float* wtg     = (float*)alloc(128 * 128 * 4);
    float* a_src   = (float*)alloc((size_t)n * NHEADS * 4);
    float* a_dst   = (float*)alloc((size_t)n * NHEADS * 4);
    int* deg       = (int*)alloc((size_t)n * 4);
    int* cursor    = (int*)alloc((size_t)n * 4);
    int* off       = (int*)alloc(((size_t)n + 1) * 4);
    int* chunkTot  = (int*)alloc(256 * 4);
    int* chunkBase = (int*)alloc(256 * 4);
    int* flag      = (int*)alloc(256);
    int* sorted    = (int*)alloc((size_t)(E + n) * 4);

    hipMemsetAsync(deg, 0, (size_t)n * 4, stream);
    hipMemsetAsync(cursor, 0, (size_t)n * 4, stream);

    detect_dtype<<<1, 256, 0, stream>>>(ei, flag);
    wtrans<<<64, 256, 0, stream>>>(W, wtg);
    gemm_h<<<(n + 63) / 64, 256, 0, stream>>>(x, wtg, h, n);
    att_logits<<<(n * NHEADS + 255) / 256, 256, 0, stream>>>(h, att_src, att_dst, a_src, a_dst, n);
    hist<<<(E + 255) / 256, 256, 0, stream>>>(ei, flag, deg, E);
    int nchunks = (n + 2047) / 2048;
    scan1<<<nchunks, 256, 0, stream>>>(deg, off, chunkTot, n);
    scan2<<<1, 64, 0, stream>>>(chunkTot, chunkBase, nchunks);
    finalize<<<(n + 1 + 255) / 256, 256, 0, stream>>>(off, chunkBase, n, E);
    scatter<<<(E + n + 255) / 256, 256, 0, stream>>>(ei, flag, off, cursor, sorted, E, n);
    aggregate<<<2048, 256, 0, stream>>>(h, a_src, a_dst, off, sorted, bias_conv, agg, n);
    proj<<<(n + 63) / 64, 256, 0, stream>>>(agg, W_lin, b_lin, (float*)d_out, n);
}

// Round 2
// 502.763 us; speedup vs baseline: 1.0724x; 1.0724x over previous
//
#include <hip/hip_runtime.h>
#include <cstdint>
#include <cstddef>

#define NHEADS 4
#define OUT_C 32
#define HC 128          // NHEADS*OUT_C
#define IN_CH 128
#define NEG_SLOPE 0.2f

static inline size_t align256(size_t v) { return (v + 255) & ~(size_t)255; }

__device__ __forceinline__ float lrelu(float v) { return v > 0.f ? v : NEG_SLOPE * v; }

__device__ __forceinline__ float wred_max(float v) {
    v = fmaxf(v, __shfl_xor(v, 1));
    v = fmaxf(v, __shfl_xor(v, 2));
    v = fmaxf(v, __shfl_xor(v, 4));
    v = fmaxf(v, __shfl_xor(v, 8));
    v = fmaxf(v, __shfl_xor(v, 16));
    v = fmaxf(v, __shfl_xor(v, 32));
    return v;
}
__device__ __forceinline__ float wred_sum(float v) {
    v += __shfl_xor(v, 1);
    v += __shfl_xor(v, 2);
    v += __shfl_xor(v, 4);
    v += __shfl_xor(v, 8);
    v += __shfl_xor(v, 16);
    v += __shfl_xor(v, 32);
    return v;
}

// ---------------------------------------------------------------------------
// Detect whether edge_index is int64 (odd 4B words all zero for values<2^31)
// or int32. Writes flag=1 for int64, 0 for int32.
__global__ void detect_dtype(const int* __restrict__ ei, int* __restrict__ flag) {
    __shared__ int red[256];
    int t = threadIdx.x;
    int acc = 0;
    for (int i = t; i < 1024; i += 256) acc |= ei[2 * i + 1];
    red[t] = acc;
    __syncthreads();
    for (int s = 128; s > 0; s >>= 1) {
        if (t < s) red[t] |= red[t + s];
        __syncthreads();
    }
    if (t == 0) *flag = (red[0] == 0) ? 1 : 0;
}

// ---------------------------------------------------------------------------
// W [128 out][128 in] -> wt [k][o] transposed copy (tiny)
__global__ void wtrans(const float* __restrict__ W, float* __restrict__ wt) {
    int idx = blockIdx.x * 256 + threadIdx.x;
    if (idx < 128 * 128) {
        int k = idx >> 7, o = idx & 127;
        wt[idx] = W[o * 128 + k];
    }
}

// ---------------------------------------------------------------------------
// h[n][128] = x[n][128] @ W^T   (fp32 VALU GEMM, 64 rows/block)
__global__ __launch_bounds__(256) void gemm_h(const float* __restrict__ x,
                                              const float* __restrict__ wtg,
                                              float* __restrict__ h, int n) {
    __shared__ float xs[64][132];   // +4 pad: kills bank conflicts on row reads
    __shared__ float wt[32][132];
    int tid = threadIdx.x;
    int rowbase = blockIdx.x << 6;
    const float4* x4 = (const float4*)x;
#pragma unroll
    for (int i = 0; i < 8; ++i) {
        int f4 = (i << 8) + tid;          // 0..2047
        int r = f4 >> 5, cc = (f4 & 31) << 2;
        int row = rowbase + r;
        if (row >= n) row = n - 1;        // clamp; stores guarded below
        float4 v = x4[((size_t)row << 5) + (cc >> 2)];
        *(float4*)&xs[r][cc] = v;
    }
    int rg = tid >> 4, cg = tid & 15;     // 16 row-groups x 16 col-groups
    float acc[4][8];
#pragma unroll
    for (int a = 0; a < 4; ++a)
#pragma unroll
        for (int b = 0; b < 8; ++b) acc[a][b] = 0.f;

    for (int kc = 0; kc < 128; kc += 32) {
        __syncthreads();
        const float4* wg4 = (const float4*)(wtg + (size_t)kc * 128);
#pragma unroll
        for (int i = 0; i < 4; ++i) {
            int f4 = (i << 8) + tid;      // 0..1023
            int kk = f4 >> 5, oo = (f4 & 31) << 2;
            *(float4*)&wt[kk][oo] = wg4[f4];
        }
        __syncthreads();
#pragma unroll
        for (int k = 0; k < 32; k += 4) {
            float xk[4][4];
#pragma unroll
            for (int rr = 0; rr < 4; ++rr) {
                float4 t = *(const float4*)&xs[(rg << 2) + rr][kc + k];
                xk[rr][0] = t.x; xk[rr][1] = t.y; xk[rr][2] = t.z; xk[rr][3] = t.w;
            }
#pragma unroll
            for (int kk = 0; kk < 4; ++kk) {
                float4 wa = *(const float4*)&wt[k + kk][cg << 3];
                float4 wb = *(const float4*)&wt[k + kk][(cg << 3) + 4];
                float wv[8] = {wa.x, wa.y, wa.z, wa.w, wb.x, wb.y, wb.z, wb.w};
#pragma unroll
                for (int rr = 0; rr < 4; ++rr)
#pragma unroll
                    for (int jj = 0; jj < 8; ++jj)
                        acc[rr][jj] = fmaf(xk[rr][kk], wv[jj], acc[rr][jj]);
            }
        }
    }
#pragma unroll
    for (int rr = 0; rr < 4; ++rr) {
        int row = rowbase + (rg << 2) + rr;
        if (row < n) {
            float4 o1 = {acc[rr][0], acc[rr][1], acc[rr][2], acc[rr][3]};
            float4 o2 = {acc[rr][4], acc[rr][5], acc[rr][6], acc[rr][7]};
            float4* hp = (float4*)(h + ((size_t)row << 7) + (cg << 3));
            hp[0] = o1;
            hp[1] = o2;
        }
    }
}

// ---------------------------------------------------------------------------
// a_src[n][h] = <h[n][h*32:+32], att_src[h]>, same for dst
__global__ void att_logits(const float* __restrict__ h, const float* __restrict__ att_src,
                           const float* __restrict__ att_dst, float* __restrict__ a_src,
                           float* __restrict__ a_dst, int n) {
    int idx = blockIdx.x * 256 + threadIdx.x;
    if (idx >= n * NHEADS) return;
    int hd = idx & 3;
    const float4* hp = (const float4*)(h + ((size_t)(idx >> 2) << 7) + (hd << 5));
    const float4* av4 = (const float4*)(att_src + (hd << 5));
    const float4* bv4 = (const float4*)(att_dst + (hd << 5));
    float ss = 0.f, dd = 0.f;
#pragma unroll
    for (int j = 0; j < 8; ++j) {
        float4 hv = hp[j];
        float4 av = av4[j];
        float4 bv = bv4[j];
        ss += hv.x * av.x + hv.y * av.y + hv.z * av.z + hv.w * av.w;
        dd += hv.x * bv.x + hv.y * bv.y + hv.z * bv.z + hv.w * bv.w;
    }
    a_src[idx] = ss;
    a_dst[idx] = dd;
}

// ---------------------------------------------------------------------------
// histogram of dst (edges only; self-loops added as +1 in scan)
__global__ void hist(const int* __restrict__ ei, const int* __restrict__ flag,
                     int* __restrict__ deg, int E) {
    int i = blockIdx.x * 256 + threadIdx.x;
    if (i >= E) return;
    int f64 = *flag;
    int d = f64 ? ei[2 * ((size_t)E + i)] : ei[(size_t)E + i];
    atomicAdd(&deg[d], 1);
}

// chunked exclusive scan, chunk=2048 (256 thr x 8)
__global__ void scan1(const int* __restrict__ deg, int* __restrict__ off,
                      int* __restrict__ tot, int n) {
    __shared__ int ts[256];
    int t = threadIdx.x;
    int i0 = (blockIdx.x << 11) + (t << 3);
    int pref[8];
    int sum = 0;
#pragma unroll
    for (int j = 0; j < 8; ++j) {
        int i = i0 + j;
        int v = (i < n) ? (deg[i] + 1) : 0;  // +1 = self loop
        pref[j] = sum;
        sum += v;
    }
    ts[t] = sum;
    __syncthreads();
    int run = sum;
    for (int d = 1; d < 256; d <<= 1) {
        int o = (t >= d) ? ts[t - d] : 0;
        __syncthreads();
        run += o;
        ts[t] = run;
        __syncthreads();
    }
    int excl = run - sum;
#pragma unroll
    for (int j = 0; j < 8; ++j) {
        int i = i0 + j;
        if (i < n) off[i] = excl + pref[j];
    }
    if (t == 255) tot[blockIdx.x] = run;
}

__global__ void scan2(const int* __restrict__ tot, int* __restrict__ cbase, int nc) {
    int lane = threadIdx.x;  // 64 threads, 1 wave
    int carry = 0;
    for (int b = 0; b < nc; b += 64) {
        int i = b + lane;
        int v = (i < nc) ? tot[i] : 0;
        int orig = v;
        for (int d = 1; d < 64; d <<= 1) {
            int u = __shfl_up(v, d);
            if (lane >= d) v += u;
        }
        if (i < nc) cbase[i] = carry + v - orig;
        carry += __shfl(v, 63);
    }
}

__global__ void finalize(int* __restrict__ off, const int* __restrict__ cbase, int n, int E) {
    int i = blockIdx.x * 256 + threadIdx.x;
    if (i < n) off[i] += cbase[i >> 11];
    else if (i == n) off[n] = E + n;
}

__global__ void scatter(const int* __restrict__ ei, const int* __restrict__ flag,
                        const int* __restrict__ off, int* __restrict__ cursor,
                        int* __restrict__ sorted, int E, int n) {
    int i = blockIdx.x * 256 + threadIdx.x;
    if (i >= E + n) return;
    int f64 = *flag;
    int s, d;
    if (i < E) {
        if (f64) { s = ei[2 * (size_t)i]; d = ei[2 * ((size_t)E + i)]; }
        else     { s = ei[i];             d = ei[(size_t)E + i]; }
    } else {
        s = d = i - E;  // self loop
    }
    int pos = off[d] + atomicAdd(&cursor[d], 1);
    sorted[pos] = s;
}

// ---------------------------------------------------------------------------
// Inner accumulate: half-wave per edge, lane L=lane&31 owns channels 4L..4L+3.
// One dwordx4 gather per lane per edge; alpha via conflict-free LDS broadcast.
// Unroll x2 -> 4 edges / 2 independent gathers in flight.
__device__ __forceinline__ void accum_edges(const int* ssrc, const float* salpha,
                                            const float* __restrict__ h,
                                            int count, int half, int L, int head,
                                            float4& acc, float4& accb) {
    int j = 0;
    for (; j + 4 <= count; j += 4) {
        int jA = j + half, jB = jA + 2;
        int sA = ssrc[jA], sB = ssrc[jB];
        float aA = salpha[(jA << 2) + head];
        float aB = salpha[(jB << 2) + head];
        float4 hA = *(const float4*)(h + ((size_t)sA << 7) + (L << 2));
        float4 hB = *(const float4*)(h + ((size_t)sB << 7) + (L << 2));
        acc.x = fmaf(aA, hA.x, acc.x);
        acc.y = fmaf(aA, hA.y, acc.y);
        acc.z = fmaf(aA, hA.z, acc.z);
        acc.w = fmaf(aA, hA.w, acc.w);
        accb.x = fmaf(aB, hB.x, accb.x);
        accb.y = fmaf(aB, hB.y, accb.y);
        accb.z = fmaf(aB, hB.z, accb.z);
        accb.w = fmaf(aB, hB.w, accb.w);
    }
    for (; j < count; j += 2) {
        int j2 = j + half;
        if (j2 < count) {
            int sA = ssrc[j2];
            float aA = salpha[(j2 << 2) + head];
            float4 hA = *(const float4*)(h + ((size_t)sA << 7) + (L << 2));
            acc.x = fmaf(aA, hA.x, acc.x);
            acc.y = fmaf(aA, hA.y, acc.y);
            acc.z = fmaf(aA, hA.z, acc.z);
            acc.w = fmaf(aA, hA.w, acc.w);
        }
    }
}

// One wave per destination node: segment softmax + weighted aggregation.
// Per-wave LDS staging of (src, normalized alpha); wave-synchronous (no
// __syncthreads -- DS ops from one wave complete in order; asm waitcnt +
// memory clobber pins compiler ordering).
__global__ __launch_bounds__(256) void aggregate(const float* __restrict__ h,
                                                 const float* __restrict__ a_src,
                                                 const float* __restrict__ a_dst,
                                                 const int* __restrict__ off,
                                                 const int* __restrict__ sorted,
                                                 const float* __restrict__ bias,
                                                 float* __restrict__ agg, int n) {
    const float NEG_BIG = -1e30f;
    __shared__ int sh_src[4][64];
    __shared__ float sh_alpha[4][256];    // [edge][head]
    int wslot = threadIdx.x >> 6;
    int lane = threadIdx.x & 63;
    int wid = blockIdx.x * (blockDim.x >> 6) + wslot;
    int nw = gridDim.x * (blockDim.x >> 6);
    int L = lane & 31, half = lane >> 5, head = L >> 3;
    float4 b4 = ((const float4*)bias)[L];
    const float4* as4 = (const float4*)a_src;
    const float4* ad4 = (const float4*)a_dst;
    int* ssrc = sh_src[wslot];
    float* salpha = sh_alpha[wslot];

    for (int node = wid; node < n; node += nw) {
        int start = off[node], end = off[node + 1];
        int deg = end - start;          // >= 1 (self loop)
        float4 ad = ad4[node];
        float4 acc = {0.f, 0.f, 0.f, 0.f};
        float4 accb = {0.f, 0.f, 0.f, 0.f};

        if (deg <= 64) {
            bool v = lane < deg;
            int s = v ? sorted[start + lane] : sorted[start];
            float4 as = as4[s];
            float e0 = v ? lrelu(as.x + ad.x) : NEG_BIG;
            float e1 = v ? lrelu(as.y + ad.y) : NEG_BIG;
            float e2 = v ? lrelu(as.z + ad.z) : NEG_BIG;
            float e3 = v ? lrelu(as.w + ad.w) : NEG_BIG;
            float m0 = wred_max(e0), m1 = wred_max(e1);
            float m2 = wred_max(e2), m3 = wred_max(e3);
            float p0 = v ? __expf(e0 - m0) : 0.f;
            float p1 = v ? __expf(e1 - m1) : 0.f;
            float p2 = v ? __expf(e2 - m2) : 0.f;
            float p3 = v ? __expf(e3 - m3) : 0.f;
            float s0 = wred_sum(p0), s1 = wred_sum(p1);
            float s2 = wred_sum(p2), s3 = wred_sum(p3);
            float4 al = {p0 / s0, p1 / s1, p2 / s2, p3 / s3};
            ssrc[lane] = s;
            *(float4*)&salpha[lane << 2] = al;
            asm volatile("s_waitcnt lgkmcnt(0)" ::: "memory");
            accum_edges(ssrc, salpha, h, deg, half, L, head, acc, accb);
        } else {
            // general chunked path (rare on this graph: mean deg ~17)
            float m0 = NEG_BIG, m1 = NEG_BIG, m2 = NEG_BIG, m3 = NEG_BIG;
            for (int bb = 0; bb < deg; bb += 64) {
                int i = bb + lane;
                bool v = i < deg;
                int s = v ? sorted[start + i] : sorted[start];
                float4 as = as4[s];
                if (v) {
                    m0 = fmaxf(m0, lrelu(as.x + ad.x));
                    m1 = fmaxf(m1, lrelu(as.y + ad.y));
                    m2 = fmaxf(m2, lrelu(as.z + ad.z));
                    m3 = fmaxf(m3, lrelu(as.w + ad.w));
                }
            }
            m0 = wred_max(m0); m1 = wred_max(m1); m2 = wred_max(m2); m3 = wred_max(m3);
            float s0 = 0.f, s1 = 0.f, s2 = 0.f, s3 = 0.f;
            for (int bb = 0; bb < deg; bb += 64) {
                int i = bb + lane;
                bool v = i < deg;
                int s = v ? sorted[start + i] : sorted[start];
                float4 as = as4[s];
                if (v) {
                    s0 += __expf(lrelu(as.x + ad.x) - m0);
                    s1 += __expf(lrelu(as.y + ad.y) - m1);
                    s2 += __expf(lrelu(as.z + ad.z) - m2);
                    s3 += __expf(lrelu(as.w + ad.w) - m3);
                }
            }
            s0 = wred_sum(s0); s1 = wred_sum(s1);
            s2 = wred_sum(s2); s3 = wred_sum(s3);
            float i0 = 1.f / s0, i1 = 1.f / s1, i2 = 1.f / s2, i3 = 1.f / s3;
            for (int bb = 0; bb < deg; bb += 64) {
                int i = bb + lane;
                bool v = i < deg;
                int s = v ? sorted[start + i] : sorted[start];
                float4 as = as4[s];
                float4 al;
                al.x = v ? __expf(lrelu(as.x + ad.x) - m0) * i0 : 0.f;
                al.y = v ? __expf(lrelu(as.y + ad.y) - m1) * i1 : 0.f;
                al.z = v ? __expf(lrelu(as.z + ad.z) - m2) * i2 : 0.f;
                al.w = v ? __expf(lrelu(as.w + ad.w) - m3) * i3 : 0.f;
                ssrc[lane] = s;
                *(float4*)&salpha[lane << 2] = al;
                asm volatile("s_waitcnt lgkmcnt(0)" ::: "memory");
                int cl = deg - bb;
                if (cl > 64) cl = 64;
                accum_edges(ssrc, salpha, h, cl, half, L, head, acc, accb);
                asm volatile("" ::: "memory");
            }
        }
        acc.x += accb.x; acc.y += accb.y; acc.z += accb.z; acc.w += accb.w;
        acc.x += __shfl_xor(acc.x, 32);
        acc.y += __shfl_xor(acc.y, 32);
        acc.z += __shfl_xor(acc.z, 32);
        acc.w += __shfl_xor(acc.w, 32);
        if (lane < 32) {
            float4 res = {acc.x + b4.x, acc.y + b4.y, acc.z + b4.z, acc.w + b4.w};
            *(float4*)(agg + ((size_t)node << 7) + (L << 2)) = res;
        }
    }
}

// ---------------------------------------------------------------------------
// out[n][32] = elu(agg[n][128] @ W_lin^T + b_lin)
__global__ __launch_bounds__(256) void proj(const float* __restrict__ agg,
                                            const float* __restrict__ W_lin,
                                            const float* __restrict__ b_lin,
                                            float* __restrict__ out, int n) {
    __shared__ float xs[64][132];
    __shared__ float wt[128][36];   // wt[k][o]
    int tid = threadIdx.x;
    const float4* w4 = (const float4*)W_lin;
#pragma unroll
    for (int i = 0; i < 4; ++i) {
        int f4 = (i << 8) + tid;          // 0..1023
        int o = f4 >> 5, kk = (f4 & 31) << 2;
        float4 w = w4[f4];
        wt[kk][o] = w.x;
        wt[kk + 1][o] = w.y;
        wt[kk + 2][o] = w.z;
        wt[kk + 3][o] = w.w;
    }
    int rowbase = blockIdx.x << 6;
    const float4* a4 = (const float4*)agg;
#pragma unroll
    for (int i = 0; i < 8; ++i) {
        int f4 = (i << 8) + tid;          // 0..2047
        int r = f4 >> 5, cc = (f4 & 31) << 2;
        int row = rowbase + r;
        if (row >= n) row = n - 1;
        *(float4*)&xs[r][cc] = a4[((size_t)row << 5) + (cc >> 2)];
    }
    __syncthreads();
    int r = tid >> 2, cg = tid & 3, c0 = cg << 3;
    float acc[8];
#pragma unroll
    for (int j = 0; j < 8; ++j) acc[j] = 0.f;
    for (int k = 0; k < 128; k += 4) {
        float4 xv = *(const float4*)&xs[r][k];
        float xk[4] = {xv.x, xv.y, xv.z, xv.w};
#pragma unroll
        for (int kk = 0; kk < 4; ++kk) {
            float4 wa = *(const float4*)&wt[k + kk][c0];
            float4 wb = *(const float4*)&wt[k + kk][c0 + 4];
            acc[0] = fmaf(xk[kk], wa.x, acc[0]);
            acc[1] = fmaf(xk[kk], wa.y, acc[1]);
            acc[2] = fmaf(xk[kk], wa.z, acc[2]);
            acc[3] = fmaf(xk[kk], wa.w, acc[3]);
            acc[4] = fmaf(xk[kk], wb.x, acc[4]);
            acc[5] = fmaf(xk[kk], wb.y, acc[5]);
            acc[6] = fmaf(xk[kk], wb.z, acc[6]);
            acc[7] = fmaf(xk[kk], wb.w, acc[7]);
        }
    }
    int row = rowbase + r;
    if (row < n) {
        float res[8];
#pragma unroll
        for (int j = 0; j < 8; ++j) {
            float v = acc[j] + b_lin[c0 + j];
            res[j] = v > 0.f ? v : (__expf(v) - 1.f);
        }
        float4* op = (float4*)(out + (size_t)row * 32 + c0);
        op[0] = make_float4(res[0], res[1], res[2], res[3]);
        op[1] = make_float4(res[4], res[5], res[6], res[7]);
    }
}

// ---------------------------------------------------------------------------
extern "C" void kernel_launch(void* const* d_in, const int* in_sizes, int n_in,
                              void* d_out, int out_size, void* d_ws, size_t ws_size,
                              hipStream_t stream) {
    const float* x = (const float*)d_in[0];
    const int* ei = (const int*)d_in[1];
    const float* W = (const float*)d_in[2];
    const float* att_src = (const float*)d_in[3];
    const float* att_dst = (const float*)d_in[4];
    const float* bias_conv = (const float*)d_in[5];
    const float* W_lin = (const float*)d_in[6];
    const float* b_lin = (const float*)d_in[7];
    int n = in_sizes[0] / IN_CH;
    int E = in_sizes[1] / 2;

    char* ws = (char*)d_ws;
    size_t o = 0;
    auto alloc = [&](size_t bytes) { char* p = ws + o; o = align256(o + bytes); return p; };
    float* h       = (float*)alloc((size_t)n * HC * 4);
    float* agg     = (float*)alloc((size_t)n * HC * 4);
    float* wtg     = (float*)alloc(128 * 128 * 4);
    float* a_src   = (float*)alloc((size_t)n * NHEADS * 4);
    float* a_dst   = (float*)alloc((size_t)n * NHEADS * 4);
    int* deg       = (int*)alloc((size_t)n * 4);
    int* cursor    = (int*)alloc((size_t)n * 4);
    int* off       = (int*)alloc(((size_t)n + 1) * 4);
    int* chunkTot  = (int*)alloc(256 * 4);
    int* chunkBase = (int*)alloc(256 * 4);
    int* flag      = (int*)alloc(256);
    int* sorted    = (int*)alloc((size_t)(E + n) * 4);

    hipMemsetAsync(deg, 0, (size_t)n * 4, stream);
    hipMemsetAsync(cursor, 0, (size_t)n * 4, stream);

    detect_dtype<<<1, 256, 0, stream>>>(ei, flag);
    wtrans<<<64, 256, 0, stream>>>(W, wtg);
    gemm_h<<<(n + 63) / 64, 256, 0, stream>>>(x, wtg, h, n);
    att_logits<<<(n * NHEADS + 255) / 256, 256, 0, stream>>>(h, att_src, att_dst, a_src, a_dst, n);
    hist<<<(E + 255) / 256, 256, 0, stream>>>(ei, flag, deg, E);
    int nchunks = (n + 2047) / 2048;
    scan1<<<nchunks, 256, 0, stream>>>(deg, off, chunkTot, n);
    scan2<<<1, 64, 0, stream>>>(chunkTot, chunkBase, nchunks);
    finalize<<<(n + 1 + 255) / 256, 256, 0, stream>>>(off, chunkBase, n, E);
    scatter<<<(E + n + 255) / 256, 256, 0, stream>>>(ei, flag, off, cursor, sorted, E, n);
    aggregate<<<2048, 256, 0, stream>>>(h, a_src, a_dst, off, sorted, bias_conv, agg, n);
    proj<<<(n + 63) / 64, 256, 0, stream>>>(agg, W_lin, b_lin, (float*)d_out, n);
}